// Round 13
// baseline (1283.314 us; speedup 1.0000x reference)
//
#include <hip/hip_runtime.h>
#include <hip/hip_fp16.h>
#include <math.h>

#define T_ 12
#define N_ 20000
#define E_ 320000
#define FIN_ 128
#define H_ 256
#define G_ 256
#define C_ 10
#define ECH 8
#define EPC (E_ / ECH)   // 40000 edges per chunk
#define NB 20            // node buckets of 1024 (bucket = node >> 10)
#define BNODES 1024
#define CAPF 20480       // fillB2 LDS staging recs (mean 16384, +32 sigma)

typedef __attribute__((ext_vector_type(8))) short bf16x8;
typedef __attribute__((ext_vector_type(4))) float f32x4;

// ---------------- workspace layout (bytes) ----------------
static const size_t OFF_EMB   = 0;          // T*256 f32 (zeroed each launch)
static const size_t ZERO_BYTES= 12288;
static const size_t OFF_DINV  = 12288;      // T*N f32                     -> 972288
static const size_t OFF_CP    = 972288;     // T*(N+1) i32 (pad 960256)    -> 1932544
static const size_t OFF_DEGP  = 1932544;    // T*ECH*N f32 [dead after scanT]
static const size_t OFF_CNT16 = 9612544;    // T*ECH*N u16 [dead after pcount]
static const size_t OFF_EBIN  = 1932544;    // T*E uint2 (ALIASES degp+cnt16) -> 32652544
                                            // after fillB2 (in-place): CSR {row u32, nm f32}
static const size_t OFF_PCNT  = 32652544;   // T*ECH*NB u32                -> 32660224
static const size_t OFF_POFF  = 32660224;   // T*168 u32                   -> 32668288
static const size_t OFF_W1BT  = 48028288;   // 256x128 bf16
static const size_t OFF_W2BT  = 48093824;   // 256x256 bf16
static const size_t OFF_WIHT  = 48224896;   // 256x768 f32
static const size_t OFF_WHHT  = 49011328;   // 256x768 f32
static const size_t OFF_GX    = 49797760;   // 12x768 f32
static const size_t OFF_RA    = 49834624;   // region A: NT*10.24MB (xbt then Q)
static const size_t PER_T_FULL= 10240000;   // N*256*2

__device__ __forceinline__ float bf2f(unsigned short u) {
  return __uint_as_float(((unsigned int)u) << 16);
}
__device__ __forceinline__ unsigned short f2bf(float f) {
  unsigned int u = __float_as_uint(f);
  unsigned int r = (u + 0x7FFFu + ((u >> 16) & 1u)) >> 16;  // RNE
  return (unsigned short)r;
}
__device__ __forceinline__ float bflo(unsigned int u) { return __uint_as_float(u << 16); }
__device__ __forceinline__ float bfhi(unsigned int u) { return __uint_as_float(u & 0xFFFF0000u); }
__device__ __forceinline__ unsigned int packbf(float lo, float hi) {
  return (unsigned int)f2bf(lo) | ((unsigned int)f2bf(hi) << 16);
}

// ---------------- partial histogram: block (t, ech) owns edges [ech*EPC, +EPC) ----------------
__global__ __launch_bounds__(1024) void histp(const int* __restrict__ ei,
                                              const float* __restrict__ ea,
                                              float* __restrict__ degp,
                                              unsigned short* __restrict__ cnt16) {
  __shared__ float degs[N_];            // 80 KB
  __shared__ unsigned int cntp[N_ / 2]; // 40 KB
  const int t = blockIdx.x, ech = blockIdx.y;
  const int tid = threadIdx.x;
  for (int i = tid; i < N_; i += 1024) degs[i] = 0.f;
  for (int i = tid; i < N_ / 2; i += 1024) cntp[i] = 0u;
  __syncthreads();
  const int* col = ei + (size_t)t * 2 * E_ + E_ + ech * EPC;
  const float* wt = ea + (size_t)t * E_ + ech * EPC;
  for (int e = tid; e < EPC; e += 1024) {
    int c = col[e];
    atomicAdd(&degs[c], wt[e]);
    atomicAdd(&cntp[c >> 1], 1u << ((c & 1) * 16));
  }
  __syncthreads();
  float* dp = degp + ((size_t)t * ECH + ech) * N_;
  unsigned short* cp16 = cnt16 + ((size_t)t * ECH + ech) * N_;
  for (int i = tid; i < N_; i += 1024) {
    dp[i] = degs[i];
    cp16[i] = (unsigned short)((cntp[i >> 1] >> ((i & 1) * 16)) & 0xFFFFu);
  }
}

// ---------------- sum partials, scan -> colptr, dinv ----------------
__global__ __launch_bounds__(1024) void scanT(const unsigned short* __restrict__ cnt16,
                                              const float* __restrict__ degp,
                                              int* __restrict__ colptr,
                                              float* __restrict__ dinv) {
  const int t = blockIdx.x;
  __shared__ int s[1024];
  const int tid = threadIdx.x;
  int base = 0;
  for (int c0 = 0; c0 < N_; c0 += 1024) {
    int n = c0 + tid;
    int tot = 0;
    float dg = 0.f;
    if (n < N_) {
#pragma unroll
      for (int ch = 0; ch < ECH; ++ch) {
        tot += cnt16[((size_t)t * ECH + ch) * N_ + n];
        dg += degp[((size_t)t * ECH + ch) * N_ + n];
      }
    }
    s[tid] = tot;
    __syncthreads();
    for (int off = 1; off < 1024; off <<= 1) {
      int add = (tid >= off) ? s[tid - off] : 0;
      __syncthreads();
      s[tid] += add;
      __syncthreads();
    }
    if (n < N_) {
      colptr[t * (N_ + 1) + n] = base + s[tid] - tot;
      dinv[t * N_ + n] = rsqrtf(dg + 1.0f);
    }
    base += s[1023];
    __syncthreads();
  }
  if (tid == 0) colptr[t * (N_ + 1) + N_] = base;
}

// ---------------- bucket counts per (t, ech) ----------------
__global__ __launch_bounds__(256) void pcount(const unsigned short* __restrict__ cnt16,
                                              unsigned int* __restrict__ pcnt) {
  __shared__ unsigned int psum[NB];
  const int t = blockIdx.x, ech = blockIdx.y;
  const int tid = threadIdx.x;
  if (tid < NB) psum[tid] = 0u;
  __syncthreads();
  const unsigned short* cc = cnt16 + ((size_t)t * ECH + ech) * N_;
  for (int c0 = 0; c0 < N_; c0 += 256) {
    int n = c0 + tid;
    unsigned int v = (n < N_) ? (unsigned int)cc[n] : 0u;
#pragma unroll
    for (int off = 32; off; off >>= 1) v += __shfl_down(v, off, 64);
    if ((tid & 63) == 0) atomicAdd(&psum[c0 >> 10], v);
  }
  __syncthreads();
  if (tid < NB) pcnt[((size_t)t * ECH + ech) * NB + tid] = psum[tid];
}

// ---------------- per-(bucket, chunk) stream offsets ----------------
__global__ void partS(const unsigned int* __restrict__ pcnt,
                      unsigned int* __restrict__ poff) {
  const int t = threadIdx.x;
  if (t >= T_) return;
  unsigned int run = 0;
  for (int b = 0; b < NB; ++b)
    for (int ech = 0; ech < ECH; ++ech) {
      poff[t * 168 + b * 8 + ech] = run;
      run += pcnt[((size_t)t * ECH + ech) * NB + b];
    }
  poff[t * 168 + 160] = run;
}

// ---------------- partition scatter: each edge touched once ----------------
__global__ __launch_bounds__(512) void partW(const int* __restrict__ ei,
                                             const float* __restrict__ ea,
                                             const float* __restrict__ dinv,
                                             const unsigned int* __restrict__ poff,
                                             uint2* __restrict__ ebin) {
  __shared__ unsigned int cursor[NB];
  const int t = blockIdx.x, ech = blockIdx.y;
  const int tid = threadIdx.x;
  if (tid < NB) cursor[tid] = poff[t * 168 + tid * 8 + ech];
  __syncthreads();
  const int eoff = ech * EPC;
  const int* rowp = ei + (size_t)t * 2 * E_ + eoff;
  const int* colp = rowp + E_;
  const float* wt = ea + (size_t)t * E_ + eoff;
  const float* dv = dinv + (size_t)t * N_;
  uint2* eb = ebin + (size_t)t * E_;
  for (int e = tid; e < EPC; e += 512) {
    int c = colp[e], r = rowp[e];
    float nm = dv[r] * wt[e] * dv[c];
    unsigned int pos = atomicAdd(&cursor[c >> 10], 1u);
    uint2 rec;
    rec.x = (unsigned int)(c & 1023) | ((unsigned int)r << 16);
    rec.y = (unsigned int)__half_as_ushort(__float2half(nm));
    eb[pos] = rec;
  }
}

// ---------------- CSR fill IN-PLACE: bucket-local LDS scatter; expand to {row, nm f32} ----------------
__global__ __launch_bounds__(512) void fillB2(uint2* __restrict__ ebin,
                                              const int* __restrict__ colptr) {
  __shared__ unsigned int data[CAPF];   // 80 KB packed (row u16 | nm f16)
  __shared__ unsigned int offp[BNODES]; // 4 KB
  const int t = blockIdx.x, b = blockIdx.y;
  const int tid = threadIdx.x;
  const int nlo = b << 10;
  const int nnodes = (N_ - nlo < BNODES) ? (N_ - nlo) : BNODES;
  const int* cp = colptr + t * (N_ + 1);
  const int base = cp[nlo];
  const int bsize = cp[nlo + nnodes] - base;
  for (int i = tid; i < nnodes; i += 512) offp[i] = (unsigned int)(cp[nlo + i] - base);
  __syncthreads();
  uint2* eb = ebin + (size_t)t * E_ + base;
  for (int i = tid; i < bsize; i += 512) {
    uint2 rec = eb[i];
    unsigned int cl = rec.x & 0xFFFFu;
    unsigned int rec4 = (rec.x >> 16) | (rec.y << 16);  // row | f16nm<<16
    unsigned int pos = atomicAdd(&offp[cl], 1u);
    if (pos < CAPF) data[pos] = rec4;  // CAPF = +32 sigma: overflow unreachable
  }
  __syncthreads();  // all reads of eb complete before in-place writes
  const int lim = bsize < CAPF ? bsize : CAPF;
  for (int i = tid; i < lim; i += 512) {
    unsigned int rec4 = data[i];
    uint2 o;
    o.x = rec4 & 0xFFFFu;  // row
    o.y = __float_as_uint(__half2float(__ushort_as_half((unsigned short)(rec4 >> 16))));
    eb[i] = o;
  }
}

// ---------------- weight prep ----------------
__global__ __launch_bounds__(256) void prep_kernel(const float* __restrict__ W1,
                                                   const float* __restrict__ W2,
                                                   const float* __restrict__ Wih,
                                                   const float* __restrict__ Whh,
                                                   unsigned short* __restrict__ W1bT,
                                                   unsigned short* __restrict__ W2bT,
                                                   float* __restrict__ WihT,
                                                   float* __restrict__ WhhT) {
  int idx = blockIdx.x * 256 + threadIdx.x;
  if (idx < 32768) {
    int n = idx >> 7, k = idx & 127;
    W1bT[idx] = f2bf(W1[k * 256 + n]);
  } else if (idx < 98304) {
    int j = idx - 32768;
    int n = j >> 8, k = j & 255;
    W2bT[j] = f2bf(W2[k * 256 + n]);
  } else if (idx < 294912) {
    int j = idx - 98304;
    int k = j / 768, c = j - k * 768;
    WihT[j] = Wih[c * 256 + k];
  } else if (idx < 491520) {
    int j = idx - 294912;
    int k = j / 768, c = j - k * 768;
    WhhT[j] = Whh[c * 256 + k];
  }
}

// ---------------- cast x_t fp32 -> bf16 (y = local t) ----------------
__global__ __launch_bounds__(256) void castx_kernel(const float* __restrict__ x,
                                                    unsigned short* __restrict__ xb,
                                                    int t_base) {
  const int tl = blockIdx.y;
  const int t = t_base + tl;
  const size_t q = (size_t)blockIdx.x * 256 + threadIdx.x;
  float4 v = ((const float4*)x)[(size_t)t * (N_ * FIN_ / 4) + q];
  ushort4 o;
  o.x = f2bf(v.x); o.y = f2bf(v.y); o.z = f2bf(v.z); o.w = f2bf(v.w);
  ((ushort4*)xb)[(size_t)tl * (N_ * FIN_ / 4) + q] = o;
}

// ---------------- lean channel-split gather ----------------
// wave = one (node, pass of 128 ch); lane owns 4 ch (8B load); 2 edges in flight
// (32 lanes each); recs pre-expanded {row u32, nm f32} -> ~2 decode ops/visit;
// combine = single xor-32 round over 4 accumulators.
template <int CHN, int NPASS>
__global__ __launch_bounds__(256) void aggD(const unsigned short* __restrict__ h,
                                            unsigned short* __restrict__ o,
                                            const uint2* __restrict__ erec2,
                                            const int* __restrict__ colptr,
                                            const float* __restrict__ dinv,
                                            int t_base, int nt) {
  int bid = blockIdx.x;
  int L = bid;
  if (nt > 1) {
    int chunk = (int)(gridDim.x >> 3);
    L = (bid & 7) * chunk + (bid >> 3);
  }
  const int PT = NPASS * 5000;
  const int tl = L / PT;
  int rem = L - tl * PT;
  const int pass = rem / 5000;
  const int nb = rem - pass * 5000;
  const int node = nb * 4 + ((int)threadIdx.x >> 6);
  const int t = t_base + tl;
  const int hh = ((int)threadIdx.x >> 5) & 1;   // edge parity
  const int l32 = threadIdx.x & 31;             // 4-ch slot within pass
  const int me = threadIdx.x & 63;
  const uint2* ert = erec2 + (size_t)t * E_;
  const int* cp = colptr + t * (N_ + 1);
  const unsigned short* ht = h + (size_t)tl * N_ * CHN + pass * 128 + l32 * 4;
  float a0 = 0.f, a1 = 0.f, a2 = 0.f, a3 = 0.f;
  const int s0 = cp[node], s1 = cp[node + 1];
  for (int i = s0 + hh; i < s1; i += 2) {
    const uint2 rec = ert[i];
    const float nm = __uint_as_float(rec.y);
    uint2 u = *(const uint2*)&ht[(size_t)rec.x * CHN];
    a0 = fmaf(nm, bflo(u.x), a0); a1 = fmaf(nm, bfhi(u.x), a1);
    a2 = fmaf(nm, bflo(u.y), a2); a3 = fmaf(nm, bfhi(u.y), a3);
  }
  if (hh == 0) {
    const float di = dinv[(size_t)t * N_ + node];
    const float sw = di * di;
    uint2 us = *(const uint2*)&ht[(size_t)node * CHN];
    a0 = fmaf(sw, bflo(us.x), a0); a1 = fmaf(sw, bfhi(us.x), a1);
    a2 = fmaf(sw, bflo(us.y), a2); a3 = fmaf(sw, bfhi(us.y), a3);
  }
  a0 += __shfl(a0, me ^ 32, 64); a1 += __shfl(a1, me ^ 32, 64);
  a2 += __shfl(a2, me ^ 32, 64); a3 += __shfl(a3, me ^ 32, 64);
  if (hh == 0) {
    uint2 ov;
    ov.x = packbf(a0, a1); ov.y = packbf(a2, a3);
    unsigned short* ot = o + (size_t)tl * N_ * CHN + pass * 128 + l32 * 4;
    *(uint2*)&ot[(size_t)node * CHN] = ov;
  }
}

// ---------------- bf16 MFMA GEMM (z = local t); MEAN fuses column-mean ----------------
template <int K, bool MEAN>
__global__ __launch_bounds__(256) void gemm_bf16(const unsigned short* __restrict__ A,
                                                 const unsigned short* __restrict__ BT,
                                                 const float* __restrict__ bias,
                                                 unsigned short* __restrict__ C,
                                                 float* __restrict__ embp,
                                                 int t_base) {
  constexpr int LD = K + 8;
  __shared__ unsigned short As[64 * LD];
  __shared__ float cs[128];
  const int tid = threadIdx.x;
  const int tl = blockIdx.z;
  const int bm = blockIdx.x * 64;
  const int bn = blockIdx.y * 128;
  const unsigned short* At = A + (size_t)tl * N_ * K;
  if (MEAN && tid < 128) cs[tid] = 0.f;
  {
    constexpr int CPR = K / 8;
    constexpr int CH = 64 * CPR / 256;
#pragma unroll
    for (int i = 0; i < CH; ++i) {
      int chunk = tid + i * 256;
      int r = chunk / CPR;
      int ck = (chunk - r * CPR) * 8;
      int row = bm + r;
      if (row >= N_) row = N_ - 1;
      *(bf16x8*)&As[r * LD + ck] = *(const bf16x8*)&At[(size_t)row * K + ck];
    }
  }
  __syncthreads();
  const int w = tid >> 6, l = tid & 63;
  const int l16 = l & 15, lk = l >> 4;
  const int rbase = (w >> 1) * 32;
  const int colbase = bn + (w & 1) * 64;
  f32x4 acc[2][4] = {};
  for (int ks = 0; ks < K; ks += 32) {
    bf16x8 a[2], b[4];
#pragma unroll
    for (int m = 0; m < 2; ++m)
      a[m] = *(const bf16x8*)&As[(rbase + m * 16 + l16) * LD + ks + lk * 8];
#pragma unroll
    for (int n = 0; n < 4; ++n)
      b[n] = *(const bf16x8*)&BT[(size_t)(colbase + n * 16 + l16) * K + ks + lk * 8];
#pragma unroll
    for (int m = 0; m < 2; ++m)
#pragma unroll
      for (int n = 0; n < 4; ++n)
        acc[m][n] = __builtin_amdgcn_mfma_f32_16x16x32_bf16(a[m], b[n], acc[m][n], 0, 0, 0);
  }
#pragma unroll
  for (int n = 0; n < 4; ++n) {
    int col = colbase + n * 16 + l16;
    float bv = bias[col];
    float psum = 0.f;
#pragma unroll
    for (int m = 0; m < 2; ++m) {
      int row0 = bm + rbase + m * 16 + lk * 4;
#pragma unroll
      for (int r = 0; r < 4; ++r) {
        int row = row0 + r;
        if (row < N_) {
          float v = fmaxf(acc[m][n][r] + bv, 0.f);
          if (MEAN) psum += v;
          else C[((size_t)tl * N_ + row) * 256 + col] = f2bf(v);
        }
      }
    }
    if (MEAN) atomicAdd(&cs[col - bn], psum);
  }
  if (MEAN) {
    __syncthreads();
    if (tid < 128)
      atomicAdd(&embp[(t_base + tl) * 256 + bn + tid], cs[tid] * (1.0f / N_));
  }
}

// ---------------- GX[t] = Wih @ emb_t + bih ----------------
__global__ __launch_bounds__(768) void gx_kernel(const float* __restrict__ emb,
                                                 const float* __restrict__ WihT,
                                                 const float* __restrict__ bih,
                                                 float* __restrict__ GX) {
  const int t = blockIdx.x;
  const int tid = threadIdx.x;
  __shared__ float se[256];
  if (tid < 256) se[tid] = emb[t * 256 + tid];
  __syncthreads();
  float p0 = 0.f, p1 = 0.f, p2 = 0.f, p3 = 0.f;
#pragma unroll 8
  for (int k = 0; k < 256; k += 4) {
    p0 = fmaf(WihT[(size_t)(k + 0) * 768 + tid], se[k + 0], p0);
    p1 = fmaf(WihT[(size_t)(k + 1) * 768 + tid], se[k + 1], p1);
    p2 = fmaf(WihT[(size_t)(k + 2) * 768 + tid], se[k + 2], p2);
    p3 = fmaf(WihT[(size_t)(k + 3) * 768 + tid], se[k + 3], p3);
  }
  GX[t * 768 + tid] = (p0 + p1) + (p2 + p3) + bih[tid];
}

// ---------------- sequential GRU + final linear ----------------
__global__ __launch_bounds__(768) void gru2_kernel(const float* __restrict__ GX,
                                                   const float* __restrict__ WhhT,
                                                   const float* __restrict__ bhh,
                                                   const float* __restrict__ Wc,
                                                   const float* __restrict__ bc,
                                                   float* __restrict__ out) {
  __shared__ float sh[256];
  __shared__ float sgh[768];
  const int tid = threadIdx.x;
  if (tid < 256) sh[tid] = 0.f;
  __syncthreads();
  for (int t = 0; t < T_; ++t) {
    float p0 = 0.f, p1 = 0.f, p2 = 0.f, p3 = 0.f;
#pragma unroll 8
    for (int k = 0; k < 256; k += 4) {
      p0 = fmaf(WhhT[(size_t)(k + 0) * 768 + tid], sh[k + 0], p0);
      p1 = fmaf(WhhT[(size_t)(k + 1) * 768 + tid], sh[k + 1], p1);
      p2 = fmaf(WhhT[(size_t)(k + 2) * 768 + tid], sh[k + 2], p2);
      p3 = fmaf(WhhT[(size_t)(k + 3) * 768 + tid], sh[k + 3], p3);
    }
    sgh[tid] = (p0 + p1) + (p2 + p3) + bhh[tid];
    __syncthreads();
    if (tid < 256) {
      const float* gx = &GX[t * 768];
      float r = 1.f / (1.f + __expf(-(gx[tid] + sgh[tid])));
      float z = 1.f / (1.f + __expf(-(gx[256 + tid] + sgh[256 + tid])));
      float n = tanhf(gx[512 + tid] + r * sgh[512 + tid]);
      sh[tid] = (1.f - z) * n + z * sh[tid];
    }
    __syncthreads();
  }
  const int wv = tid >> 6, lane = tid & 63;
  if (wv < C_) {
    float p = 0.f;
#pragma unroll
    for (int i = 0; i < 4; ++i) {
      int j = lane + 64 * i;
      p += sh[j] * Wc[(size_t)j * C_ + wv];
    }
    for (int off = 32; off > 0; off >>= 1) p += __shfl_down(p, off);
    if (lane == 0) out[wv] = p + bc[wv];
  }
}

extern "C" void kernel_launch(void* const* d_in, const int* in_sizes, int n_in,
                              void* d_out, int out_size, void* d_ws, size_t ws_size,
                              hipStream_t stream) {
  const float* x   = (const float*)d_in[0];
  const int*   ei  = (const int*)d_in[1];
  const float* ea  = (const float*)d_in[2];
  const float* W1  = (const float*)d_in[3];
  const float* b1  = (const float*)d_in[4];
  const float* W2  = (const float*)d_in[5];
  const float* b2  = (const float*)d_in[6];
  const float* Wih = (const float*)d_in[7];
  const float* Whh = (const float*)d_in[8];
  const float* bih = (const float*)d_in[9];
  const float* bhh = (const float*)d_in[10];
  const float* Wc  = (const float*)d_in[11];
  const float* bc  = (const float*)d_in[12];
  float* out = (float*)d_out;

  char* w = (char*)d_ws;
  float* emb   = (float*)(w + OFF_EMB);
  float* dinv  = (float*)(w + OFF_DINV);
  int*   cp    = (int*)(w + OFF_CP);
  float* degp  = (float*)(w + OFF_DEGP);
  unsigned short* cnt16 = (unsigned short*)(w + OFF_CNT16);
  uint2* ebin  = (uint2*)(w + OFF_EBIN);
  unsigned int* pcnt = (unsigned int*)(w + OFF_PCNT);
  unsigned int* poff = (unsigned int*)(w + OFF_POFF);
  unsigned short* W1bT = (unsigned short*)(w + OFF_W1BT);
  unsigned short* W2bT = (unsigned short*)(w + OFF_W2BT);
  float* WihT  = (float*)(w + OFF_WIHT);
  float* WhhT  = (float*)(w + OFF_WHHT);
  float* GX    = (float*)(w + OFF_GX);

  // adaptive group size: region A + region B = NT * 20.48 MB beyond OFF_RA
  int NT = 1;
  if (ws_size > OFF_RA + 2 * PER_T_FULL) {
    size_t avail = ws_size - OFF_RA;
    size_t nt = avail / (2 * PER_T_FULL);
    NT = (int)(nt < 12 ? nt : 12);
    if (NT < 1) NT = 1;
  }
  unsigned short* regA = (unsigned short*)(w + OFF_RA);
  unsigned short* regB = (unsigned short*)(w + OFF_RA + (size_t)NT * PER_T_FULL);
  unsigned short* xbt  = regA;  // NT*N*128
  unsigned short* Q    = regA;  // NT*N*256 (xbt dead by then)
  unsigned short* P128 = regB;  // NT*N*128
  unsigned short* P2   = regB;  // NT*N*256 (P128 dead by then)

  hipMemsetAsync(d_ws, 0, ZERO_BYTES, stream);

  prep_kernel<<<1920, 256, 0, stream>>>(W1, W2, Wih, Whh, W1bT, W2bT, WihT, WhhT);

  dim3 te_grid(T_, ECH);
  histp<<<te_grid, 1024, 0, stream>>>(ei, ea, degp, cnt16);
  scanT<<<T_, 1024, 0, stream>>>(cnt16, degp, cp, dinv);
  pcount<<<te_grid, 256, 0, stream>>>(cnt16, pcnt);
  partS<<<1, 64, 0, stream>>>(pcnt, poff);
  partW<<<te_grid, 512, 0, stream>>>(ei, ea, dinv, poff, ebin);
  fillB2<<<dim3(T_, NB), 512, 0, stream>>>(ebin, cp);

  for (int t0 = 0; t0 < T_; t0 += NT) {
    const int nt = (T_ - t0) < NT ? (T_ - t0) : NT;
    castx_kernel<<<dim3(2500, nt), 256, 0, stream>>>(x, xbt, t0);
    aggD<128, 1><<<nt * 5000, 256, 0, stream>>>(xbt, P128, (const uint2*)ebin, cp, dinv, t0, nt);
    gemm_bf16<FIN_, false><<<dim3(313, 2, nt), 256, 0, stream>>>(P128, W1bT, b1, Q, nullptr, t0);
    aggD<256, 2><<<nt * 10000, 256, 0, stream>>>(Q, P2, (const uint2*)ebin, cp, dinv, t0, nt);
    gemm_bf16<H_, true><<<dim3(313, 2, nt), 256, 0, stream>>>(P2, W2bT, b2, nullptr, emb, t0);
  }
  gx_kernel<<<T_, 768, 0, stream>>>(emb, WihT, bih, GX);
  gru2_kernel<<<1, 768, 0, stream>>>(GX, WhhT, bhh, Wc, bc, out);
}

// Round 14
// 1073.237 us; speedup vs baseline: 1.1957x; 1.1957x over previous
//
#include <hip/hip_runtime.h>
#include <hip/hip_fp16.h>
#include <math.h>

#define T_ 12
#define N_ 20000
#define E_ 320000
#define FIN_ 128
#define H_ 256
#define G_ 256
#define C_ 10
#define ECH 8
#define EPC (E_ / ECH)   // 40000 edges per chunk
#define NB 20            // node buckets of 1024 (bucket = node >> 10)
#define BNODES 1024
#define CAPF 20480       // fillB2 LDS staging recs (mean 16384, +32 sigma)

typedef __attribute__((ext_vector_type(8))) short bf16x8;
typedef __attribute__((ext_vector_type(4))) float f32x4;

// ---------------- workspace layout (bytes) ----------------
// compacted so OFF_RA is minimal -> NT=2 fits in ~79 MB workspace
static const size_t OFF_EMB   = 0;          // T*256 f32 (zeroed each launch)
static const size_t ZERO_BYTES= 12288;
static const size_t OFF_DINV  = 12288;      // T*N f32            -> 972288
static const size_t OFF_CP    = 972288;     // T*(N+1) i32 padded -> 1932544
static const size_t OFF_PCNT  = 1932544;    // T*ECH*NB u32       -> 1940224
static const size_t OFF_POFF  = 1940224;    // T*168 u32          -> 1948288
static const size_t OFF_W1BT  = 1948288;    // 256x128 bf16       -> 2013824
static const size_t OFF_W2BT  = 2013824;    // 256x256 bf16       -> 2144896
static const size_t OFF_WIHT  = 2144896;    // 256x768 f32        -> 2931328
static const size_t OFF_WHHT  = 2931328;    // 256x768 f32        -> 3717760
static const size_t OFF_GX    = 3717760;    // 12x768 f32         -> 3754624, pad
static const size_t OFF_EBIN  = 3754752;    // T*E uint2          -> 34474752
// DEGP (7.68MB) and CNT16 (3.84MB) alias inside EBIN: dead before partW writes
static const size_t OFF_DEGP  = 3754752;    // T*ECH*N f32  [dead after scanT]
static const size_t OFF_CNT16 = 11434752;   // T*ECH*N u16  [dead after pcount]
static const size_t OFF_RA    = 34474752;   // region A: NT*10.24MB (xbt then Q)
static const size_t PER_T_FULL= 10240000;   // N*256*2
// region B (P128 then P2) at OFF_RA + NT*PER_T_FULL; NT=2 needs OFF_RA+40.96MB = 75.4MB

__device__ __forceinline__ float bf2f(unsigned short u) {
  return __uint_as_float(((unsigned int)u) << 16);
}
__device__ __forceinline__ unsigned short f2bf(float f) {
  unsigned int u = __float_as_uint(f);
  unsigned int r = (u + 0x7FFFu + ((u >> 16) & 1u)) >> 16;  // RNE
  return (unsigned short)r;
}
__device__ __forceinline__ float bflo(unsigned int u) { return __uint_as_float(u << 16); }
__device__ __forceinline__ float bfhi(unsigned int u) { return __uint_as_float(u & 0xFFFF0000u); }
__device__ __forceinline__ unsigned int packbf(float lo, float hi) {
  return (unsigned int)f2bf(lo) | ((unsigned int)f2bf(hi) << 16);
}

// ---------------- partial histogram: block (t, ech) owns edges [ech*EPC, +EPC) ----------------
__global__ __launch_bounds__(1024) void histp(const int* __restrict__ ei,
                                              const float* __restrict__ ea,
                                              float* __restrict__ degp,
                                              unsigned short* __restrict__ cnt16) {
  __shared__ float degs[N_];            // 80 KB
  __shared__ unsigned int cntp[N_ / 2]; // 40 KB
  const int t = blockIdx.x, ech = blockIdx.y;
  const int tid = threadIdx.x;
  for (int i = tid; i < N_; i += 1024) degs[i] = 0.f;
  for (int i = tid; i < N_ / 2; i += 1024) cntp[i] = 0u;
  __syncthreads();
  const int* col = ei + (size_t)t * 2 * E_ + E_ + ech * EPC;
  const float* wt = ea + (size_t)t * E_ + ech * EPC;
  for (int e = tid; e < EPC; e += 1024) {
    int c = col[e];
    atomicAdd(&degs[c], wt[e]);
    atomicAdd(&cntp[c >> 1], 1u << ((c & 1) * 16));
  }
  __syncthreads();
  float* dp = degp + ((size_t)t * ECH + ech) * N_;
  unsigned short* cp16 = cnt16 + ((size_t)t * ECH + ech) * N_;
  for (int i = tid; i < N_; i += 1024) {
    dp[i] = degs[i];
    cp16[i] = (unsigned short)((cntp[i >> 1] >> ((i & 1) * 16)) & 0xFFFFu);
  }
}

// ---------------- sum partials, scan -> colptr, dinv ----------------
__global__ __launch_bounds__(1024) void scanT(const unsigned short* __restrict__ cnt16,
                                              const float* __restrict__ degp,
                                              int* __restrict__ colptr,
                                              float* __restrict__ dinv) {
  const int t = blockIdx.x;
  __shared__ int s[1024];
  const int tid = threadIdx.x;
  int base = 0;
  for (int c0 = 0; c0 < N_; c0 += 1024) {
    int n = c0 + tid;
    int tot = 0;
    float dg = 0.f;
    if (n < N_) {
#pragma unroll
      for (int ch = 0; ch < ECH; ++ch) {
        tot += cnt16[((size_t)t * ECH + ch) * N_ + n];
        dg += degp[((size_t)t * ECH + ch) * N_ + n];
      }
    }
    s[tid] = tot;
    __syncthreads();
    for (int off = 1; off < 1024; off <<= 1) {
      int add = (tid >= off) ? s[tid - off] : 0;
      __syncthreads();
      s[tid] += add;
      __syncthreads();
    }
    if (n < N_) {
      colptr[t * (N_ + 1) + n] = base + s[tid] - tot;
      dinv[t * N_ + n] = rsqrtf(dg + 1.0f);
    }
    base += s[1023];
    __syncthreads();
  }
  if (tid == 0) colptr[t * (N_ + 1) + N_] = base;
}

// ---------------- bucket counts per (t, ech) ----------------
__global__ __launch_bounds__(256) void pcount(const unsigned short* __restrict__ cnt16,
                                              unsigned int* __restrict__ pcnt) {
  __shared__ unsigned int psum[NB];
  const int t = blockIdx.x, ech = blockIdx.y;
  const int tid = threadIdx.x;
  if (tid < NB) psum[tid] = 0u;
  __syncthreads();
  const unsigned short* cc = cnt16 + ((size_t)t * ECH + ech) * N_;
  for (int c0 = 0; c0 < N_; c0 += 256) {
    int n = c0 + tid;
    unsigned int v = (n < N_) ? (unsigned int)cc[n] : 0u;
#pragma unroll
    for (int off = 32; off; off >>= 1) v += __shfl_down(v, off, 64);
    if ((tid & 63) == 0) atomicAdd(&psum[c0 >> 10], v);
  }
  __syncthreads();
  if (tid < NB) pcnt[((size_t)t * ECH + ech) * NB + tid] = psum[tid];
}

// ---------------- per-(bucket, chunk) stream offsets ----------------
__global__ void partS(const unsigned int* __restrict__ pcnt,
                      unsigned int* __restrict__ poff) {
  const int t = threadIdx.x;
  if (t >= T_) return;
  unsigned int run = 0;
  for (int b = 0; b < NB; ++b)
    for (int ech = 0; ech < ECH; ++ech) {
      poff[t * 168 + b * 8 + ech] = run;
      run += pcnt[((size_t)t * ECH + ech) * NB + b];
    }
  poff[t * 168 + 160] = run;
}

// ---------------- partition scatter: each edge touched once ----------------
__global__ __launch_bounds__(512) void partW(const int* __restrict__ ei,
                                             const float* __restrict__ ea,
                                             const float* __restrict__ dinv,
                                             const unsigned int* __restrict__ poff,
                                             uint2* __restrict__ ebin) {
  __shared__ unsigned int cursor[NB];
  const int t = blockIdx.x, ech = blockIdx.y;
  const int tid = threadIdx.x;
  if (tid < NB) cursor[tid] = poff[t * 168 + tid * 8 + ech];
  __syncthreads();
  const int eoff = ech * EPC;
  const int* rowp = ei + (size_t)t * 2 * E_ + eoff;
  const int* colp = rowp + E_;
  const float* wt = ea + (size_t)t * E_ + eoff;
  const float* dv = dinv + (size_t)t * N_;
  uint2* eb = ebin + (size_t)t * E_;
  for (int e = tid; e < EPC; e += 512) {
    int c = colp[e], r = rowp[e];
    float nm = dv[r] * wt[e] * dv[c];
    unsigned int pos = atomicAdd(&cursor[c >> 10], 1u);
    uint2 rec;
    rec.x = (unsigned int)(c & 1023) | ((unsigned int)r << 16);
    rec.y = (unsigned int)__half_as_ushort(__float2half(nm));
    eb[pos] = rec;
  }
}

// ---------------- CSR fill IN-PLACE: bucket-local LDS scatter; expand to {row, nm f32} ----------------
__global__ __launch_bounds__(512) void fillB2(uint2* __restrict__ ebin,
                                              const int* __restrict__ colptr) {
  __shared__ unsigned int data[CAPF];   // 80 KB packed (row u16 | nm f16)
  __shared__ unsigned int offp[BNODES]; // 4 KB
  const int t = blockIdx.x, b = blockIdx.y;
  const int tid = threadIdx.x;
  const int nlo = b << 10;
  const int nnodes = (N_ - nlo < BNODES) ? (N_ - nlo) : BNODES;
  const int* cp = colptr + t * (N_ + 1);
  const int base = cp[nlo];
  const int bsize = cp[nlo + nnodes] - base;
  for (int i = tid; i < nnodes; i += 512) offp[i] = (unsigned int)(cp[nlo + i] - base);
  __syncthreads();
  uint2* eb = ebin + (size_t)t * E_ + base;
  for (int i = tid; i < bsize; i += 512) {
    uint2 rec = eb[i];
    unsigned int cl = rec.x & 0xFFFFu;
    unsigned int rec4 = (rec.x >> 16) | (rec.y << 16);  // row | f16nm<<16
    unsigned int pos = atomicAdd(&offp[cl], 1u);
    if (pos < CAPF) data[pos] = rec4;  // CAPF = +32 sigma: overflow unreachable
  }
  __syncthreads();  // all reads of eb complete before in-place writes
  const int lim = bsize < CAPF ? bsize : CAPF;
  for (int i = tid; i < lim; i += 512) {
    unsigned int rec4 = data[i];
    uint2 o;
    o.x = rec4 & 0xFFFFu;  // row
    o.y = __float_as_uint(__half2float(__ushort_as_half((unsigned short)(rec4 >> 16))));
    eb[i] = o;
  }
}

// ---------------- weight prep ----------------
__global__ __launch_bounds__(256) void prep_kernel(const float* __restrict__ W1,
                                                   const float* __restrict__ W2,
                                                   const float* __restrict__ Wih,
                                                   const float* __restrict__ Whh,
                                                   unsigned short* __restrict__ W1bT,
                                                   unsigned short* __restrict__ W2bT,
                                                   float* __restrict__ WihT,
                                                   float* __restrict__ WhhT) {
  int idx = blockIdx.x * 256 + threadIdx.x;
  if (idx < 32768) {
    int n = idx >> 7, k = idx & 127;
    W1bT[idx] = f2bf(W1[k * 256 + n]);
  } else if (idx < 98304) {
    int j = idx - 32768;
    int n = j >> 8, k = j & 255;
    W2bT[j] = f2bf(W2[k * 256 + n]);
  } else if (idx < 294912) {
    int j = idx - 98304;
    int k = j / 768, c = j - k * 768;
    WihT[j] = Wih[c * 256 + k];
  } else if (idx < 491520) {
    int j = idx - 294912;
    int k = j / 768, c = j - k * 768;
    WhhT[j] = Whh[c * 256 + k];
  }
}

// ---------------- cast x_t fp32 -> bf16 (y = local t) ----------------
__global__ __launch_bounds__(256) void castx_kernel(const float* __restrict__ x,
                                                    unsigned short* __restrict__ xb,
                                                    int t_base) {
  const int tl = blockIdx.y;
  const int t = t_base + tl;
  const size_t q = (size_t)blockIdx.x * 256 + threadIdx.x;
  float4 v = ((const float4*)x)[(size_t)t * (N_ * FIN_ / 4) + q];
  ushort4 o;
  o.x = f2bf(v.x); o.y = f2bf(v.y); o.z = f2bf(v.z); o.w = f2bf(v.w);
  ((ushort4*)xb)[(size_t)tl * (N_ * FIN_ / 4) + q] = o;
}

// ---------------- full-sector gathers (r11 structure) + lean uint2 recs ----------------
__device__ __forceinline__ void agg_decode(int nt, int t_base, int& t, int& tl, int& node) {
  int bid = blockIdx.x;
  int L = bid;
  if (nt > 1) {
    int chunk = (int)(gridDim.x >> 3);
    L = (bid & 7) * chunk + (bid >> 3);
  }
  tl = L / 5000;
  node = (L - tl * 5000) * 4 + ((int)threadIdx.x >> 6);
  t = t_base + tl;
}

// 128-ch: quarter-wave (16 lanes x 16B) per edge, 4 edges in flight
__global__ __launch_bounds__(256) void agg128(const unsigned short* __restrict__ h,
                                              unsigned short* __restrict__ o,
                                              const uint2* __restrict__ erec2,
                                              const int* __restrict__ colptr,
                                              const float* __restrict__ dinv,
                                              int t_base, int nt) {
  int t, tl, node;
  agg_decode(nt, t_base, t, tl, node);
  const int q = ((int)threadIdx.x >> 4) & 3;
  const int l16 = threadIdx.x & 15;
  const int me = threadIdx.x & 63;
  const uint2* ert = erec2 + (size_t)t * E_;
  const int* cp = colptr + t * (N_ + 1);
  const unsigned short* ht = h + (size_t)tl * N_ * 128;
  float a0 = 0.f, a1 = 0.f, a2 = 0.f, a3 = 0.f, a4 = 0.f, a5 = 0.f, a6 = 0.f, a7 = 0.f;
  const int s0 = cp[node], s1 = cp[node + 1];
  for (int i = s0 + q; i < s1; i += 4) {
    const uint2 rec = ert[i];
    const float nm = __uint_as_float(rec.y);
    uint4 u = *(const uint4*)&ht[(size_t)rec.x * 128 + l16 * 8];
    a0 = fmaf(nm, bflo(u.x), a0); a1 = fmaf(nm, bfhi(u.x), a1);
    a2 = fmaf(nm, bflo(u.y), a2); a3 = fmaf(nm, bfhi(u.y), a3);
    a4 = fmaf(nm, bflo(u.z), a4); a5 = fmaf(nm, bfhi(u.z), a5);
    a6 = fmaf(nm, bflo(u.w), a6); a7 = fmaf(nm, bfhi(u.w), a7);
  }
  if (q == 0) {
    const float di = dinv[(size_t)t * N_ + node];
    const float sw = di * di;
    uint4 us = *(const uint4*)&ht[(size_t)node * 128 + l16 * 8];
    a0 = fmaf(sw, bflo(us.x), a0); a1 = fmaf(sw, bfhi(us.x), a1);
    a2 = fmaf(sw, bflo(us.y), a2); a3 = fmaf(sw, bfhi(us.y), a3);
    a4 = fmaf(sw, bflo(us.z), a4); a5 = fmaf(sw, bfhi(us.z), a5);
    a6 = fmaf(sw, bflo(us.w), a6); a7 = fmaf(sw, bfhi(us.w), a7);
  }
  a0 += __shfl(a0, me | 16, 64); a1 += __shfl(a1, me | 16, 64);
  a2 += __shfl(a2, me | 16, 64); a3 += __shfl(a3, me | 16, 64);
  a4 += __shfl(a4, me | 16, 64); a5 += __shfl(a5, me | 16, 64);
  a6 += __shfl(a6, me | 16, 64); a7 += __shfl(a7, me | 16, 64);
  a0 += __shfl(a0, me | 32, 64); a1 += __shfl(a1, me | 32, 64);
  a2 += __shfl(a2, me | 32, 64); a3 += __shfl(a3, me | 32, 64);
  a4 += __shfl(a4, me | 32, 64); a5 += __shfl(a5, me | 32, 64);
  a6 += __shfl(a6, me | 32, 64); a7 += __shfl(a7, me | 32, 64);
  if (q == 0 && (me >> 4) == 0) {
    uint4 ov;
    ov.x = packbf(a0, a1); ov.y = packbf(a2, a3);
    ov.z = packbf(a4, a5); ov.w = packbf(a6, a7);
    *(uint4*)&o[((size_t)tl * N_ + node) * 128 + l16 * 8] = ov;
  }
}

// 256-ch: half-wave (32 lanes x 16B) per edge, 2 edges in flight
__global__ __launch_bounds__(256) void agg256(const unsigned short* __restrict__ h,
                                              unsigned short* __restrict__ o,
                                              const uint2* __restrict__ erec2,
                                              const int* __restrict__ colptr,
                                              const float* __restrict__ dinv,
                                              int t_base, int nt) {
  int t, tl, node;
  agg_decode(nt, t_base, t, tl, node);
  const int hh = ((int)threadIdx.x >> 5) & 1;
  const int l32 = threadIdx.x & 31;
  const int me = threadIdx.x & 63;
  const uint2* ert = erec2 + (size_t)t * E_;
  const int* cp = colptr + t * (N_ + 1);
  const unsigned short* ht = h + (size_t)tl * N_ * 256;
  float a0 = 0.f, a1 = 0.f, a2 = 0.f, a3 = 0.f, a4 = 0.f, a5 = 0.f, a6 = 0.f, a7 = 0.f;
  const int s0 = cp[node], s1 = cp[node + 1];
  for (int i = s0 + hh; i < s1; i += 2) {
    const uint2 rec = ert[i];
    const float nm = __uint_as_float(rec.y);
    uint4 u = *(const uint4*)&ht[(size_t)rec.x * 256 + l32 * 8];
    a0 = fmaf(nm, bflo(u.x), a0); a1 = fmaf(nm, bfhi(u.x), a1);
    a2 = fmaf(nm, bflo(u.y), a2); a3 = fmaf(nm, bfhi(u.y), a3);
    a4 = fmaf(nm, bflo(u.z), a4); a5 = fmaf(nm, bfhi(u.z), a5);
    a6 = fmaf(nm, bflo(u.w), a6); a7 = fmaf(nm, bfhi(u.w), a7);
  }
  if (hh == 0) {
    const float di = dinv[(size_t)t * N_ + node];
    const float sw = di * di;
    uint4 us = *(const uint4*)&ht[(size_t)node * 256 + l32 * 8];
    a0 = fmaf(sw, bflo(us.x), a0); a1 = fmaf(sw, bfhi(us.x), a1);
    a2 = fmaf(sw, bflo(us.y), a2); a3 = fmaf(sw, bfhi(us.y), a3);
    a4 = fmaf(sw, bflo(us.z), a4); a5 = fmaf(sw, bfhi(us.z), a5);
    a6 = fmaf(sw, bflo(us.w), a6); a7 = fmaf(sw, bfhi(us.w), a7);
  }
  a0 += __shfl(a0, me | 32, 64); a1 += __shfl(a1, me | 32, 64);
  a2 += __shfl(a2, me | 32, 64); a3 += __shfl(a3, me | 32, 64);
  a4 += __shfl(a4, me | 32, 64); a5 += __shfl(a5, me | 32, 64);
  a6 += __shfl(a6, me | 32, 64); a7 += __shfl(a7, me | 32, 64);
  if (hh == 0) {
    uint4 ov;
    ov.x = packbf(a0, a1); ov.y = packbf(a2, a3);
    ov.z = packbf(a4, a5); ov.w = packbf(a6, a7);
    *(uint4*)&o[((size_t)tl * N_ + node) * 256 + l32 * 8] = ov;
  }
}

// ---------------- bf16 MFMA GEMM (z = local t); MEAN fuses column-mean ----------------
template <int K, bool MEAN>
__global__ __launch_bounds__(256) void gemm_bf16(const unsigned short* __restrict__ A,
                                                 const unsigned short* __restrict__ BT,
                                                 const float* __restrict__ bias,
                                                 unsigned short* __restrict__ C,
                                                 float* __restrict__ embp,
                                                 int t_base) {
  constexpr int LD = K + 8;
  __shared__ unsigned short As[64 * LD];
  __shared__ float cs[128];
  const int tid = threadIdx.x;
  const int tl = blockIdx.z;
  const int bm = blockIdx.x * 64;
  const int bn = blockIdx.y * 128;
  const unsigned short* At = A + (size_t)tl * N_ * K;
  if (MEAN && tid < 128) cs[tid] = 0.f;
  {
    constexpr int CPR = K / 8;
    constexpr int CH = 64 * CPR / 256;
#pragma unroll
    for (int i = 0; i < CH; ++i) {
      int chunk = tid + i * 256;
      int r = chunk / CPR;
      int ck = (chunk - r * CPR) * 8;
      int row = bm + r;
      if (row >= N_) row = N_ - 1;
      *(bf16x8*)&As[r * LD + ck] = *(const bf16x8*)&At[(size_t)row * K + ck];
    }
  }
  __syncthreads();
  const int w = tid >> 6, l = tid & 63;
  const int l16 = l & 15, lk = l >> 4;
  const int rbase = (w >> 1) * 32;
  const int colbase = bn + (w & 1) * 64;
  f32x4 acc[2][4] = {};
  for (int ks = 0; ks < K; ks += 32) {
    bf16x8 a[2], b[4];
#pragma unroll
    for (int m = 0; m < 2; ++m)
      a[m] = *(const bf16x8*)&As[(rbase + m * 16 + l16) * LD + ks + lk * 8];
#pragma unroll
    for (int n = 0; n < 4; ++n)
      b[n] = *(const bf16x8*)&BT[(size_t)(colbase + n * 16 + l16) * K + ks + lk * 8];
#pragma unroll
    for (int m = 0; m < 2; ++m)
#pragma unroll
      for (int n = 0; n < 4; ++n)
        acc[m][n] = __builtin_amdgcn_mfma_f32_16x16x32_bf16(a[m], b[n], acc[m][n], 0, 0, 0);
  }
#pragma unroll
  for (int n = 0; n < 4; ++n) {
    int col = colbase + n * 16 + l16;
    float bv = bias[col];
    float psum = 0.f;
#pragma unroll
    for (int m = 0; m < 2; ++m) {
      int row0 = bm + rbase + m * 16 + lk * 4;
#pragma unroll
      for (int r = 0; r < 4; ++r) {
        int row = row0 + r;
        if (row < N_) {
          float v = fmaxf(acc[m][n][r] + bv, 0.f);
          if (MEAN) psum += v;
          else C[((size_t)tl * N_ + row) * 256 + col] = f2bf(v);
        }
      }
    }
    if (MEAN) atomicAdd(&cs[col - bn], psum);
  }
  if (MEAN) {
    __syncthreads();
    if (tid < 128)
      atomicAdd(&embp[(t_base + tl) * 256 + bn + tid], cs[tid] * (1.0f / N_));
  }
}

// ---------------- GX[t] = Wih @ emb_t + bih ----------------
__global__ __launch_bounds__(768) void gx_kernel(const float* __restrict__ emb,
                                                 const float* __restrict__ WihT,
                                                 const float* __restrict__ bih,
                                                 float* __restrict__ GX) {
  const int t = blockIdx.x;
  const int tid = threadIdx.x;
  __shared__ float se[256];
  if (tid < 256) se[tid] = emb[t * 256 + tid];
  __syncthreads();
  float p0 = 0.f, p1 = 0.f, p2 = 0.f, p3 = 0.f;
#pragma unroll 8
  for (int k = 0; k < 256; k += 4) {
    p0 = fmaf(WihT[(size_t)(k + 0) * 768 + tid], se[k + 0], p0);
    p1 = fmaf(WihT[(size_t)(k + 1) * 768 + tid], se[k + 1], p1);
    p2 = fmaf(WihT[(size_t)(k + 2) * 768 + tid], se[k + 2], p2);
    p3 = fmaf(WihT[(size_t)(k + 3) * 768 + tid], se[k + 3], p3);
  }
  GX[t * 768 + tid] = (p0 + p1) + (p2 + p3) + bih[tid];
}

// ---------------- sequential GRU + final linear ----------------
__global__ __launch_bounds__(768) void gru2_kernel(const float* __restrict__ GX,
                                                   const float* __restrict__ WhhT,
                                                   const float* __restrict__ bhh,
                                                   const float* __restrict__ Wc,
                                                   const float* __restrict__ bc,
                                                   float* __restrict__ out) {
  __shared__ float sh[256];
  __shared__ float sgh[768];
  const int tid = threadIdx.x;
  if (tid < 256) sh[tid] = 0.f;
  __syncthreads();
  for (int t = 0; t < T_; ++t) {
    float p0 = 0.f, p1 = 0.f, p2 = 0.f, p3 = 0.f;
#pragma unroll 8
    for (int k = 0; k < 256; k += 4) {
      p0 = fmaf(WhhT[(size_t)(k + 0) * 768 + tid], sh[k + 0], p0);
      p1 = fmaf(WhhT[(size_t)(k + 1) * 768 + tid], sh[k + 1], p1);
      p2 = fmaf(WhhT[(size_t)(k + 2) * 768 + tid], sh[k + 2], p2);
      p3 = fmaf(WhhT[(size_t)(k + 3) * 768 + tid], sh[k + 3], p3);
    }
    sgh[tid] = (p0 + p1) + (p2 + p3) + bhh[tid];
    __syncthreads();
    if (tid < 256) {
      const float* gx = &GX[t * 768];
      float r = 1.f / (1.f + __expf(-(gx[tid] + sgh[tid])));
      float z = 1.f / (1.f + __expf(-(gx[256 + tid] + sgh[256 + tid])));
      float n = tanhf(gx[512 + tid] + r * sgh[512 + tid]);
      sh[tid] = (1.f - z) * n + z * sh[tid];
    }
    __syncthreads();
  }
  const int wv = tid >> 6, lane = tid & 63;
  if (wv < C_) {
    float p = 0.f;
#pragma unroll
    for (int i = 0; i < 4; ++i) {
      int j = lane + 64 * i;
      p += sh[j] * Wc[(size_t)j * C_ + wv];
    }
    for (int off = 32; off > 0; off >>= 1) p += __shfl_down(p, off);
    if (lane == 0) out[wv] = p + bc[wv];
  }
}

extern "C" void kernel_launch(void* const* d_in, const int* in_sizes, int n_in,
                              void* d_out, int out_size, void* d_ws, size_t ws_size,
                              hipStream_t stream) {
  const float* x   = (const float*)d_in[0];
  const int*   ei  = (const int*)d_in[1];
  const float* ea  = (const float*)d_in[2];
  const float* W1  = (const float*)d_in[3];
  const float* b1  = (const float*)d_in[4];
  const float* W2  = (const float*)d_in[5];
  const float* b2  = (const float*)d_in[6];
  const float* Wih = (const float*)d_in[7];
  const float* Whh = (const float*)d_in[8];
  const float* bih = (const float*)d_in[9];
  const float* bhh = (const float*)d_in[10];
  const float* Wc  = (const float*)d_in[11];
  const float* bc  = (const float*)d_in[12];
  float* out = (float*)d_out;

  char* w = (char*)d_ws;
  float* emb   = (float*)(w + OFF_EMB);
  float* dinv  = (float*)(w + OFF_DINV);
  int*   cp    = (int*)(w + OFF_CP);
  unsigned int* pcnt = (unsigned int*)(w + OFF_PCNT);
  unsigned int* poff = (unsigned int*)(w + OFF_POFF);
  unsigned short* W1bT = (unsigned short*)(w + OFF_W1BT);
  unsigned short* W2bT = (unsigned short*)(w + OFF_W2BT);
  float* WihT  = (float*)(w + OFF_WIHT);
  float* WhhT  = (float*)(w + OFF_WHHT);
  float* GX    = (float*)(w + OFF_GX);
  float* degp  = (float*)(w + OFF_DEGP);
  unsigned short* cnt16 = (unsigned short*)(w + OFF_CNT16);
  uint2* ebin  = (uint2*)(w + OFF_EBIN);

  // adaptive group size: region A + region B = NT * 20.48 MB beyond OFF_RA
  int NT = 1;
  if (ws_size > OFF_RA + 2 * PER_T_FULL) {
    size_t avail = ws_size - OFF_RA;
    size_t nt = avail / (2 * PER_T_FULL);
    NT = (int)(nt < 12 ? nt : 12);
    if (NT < 1) NT = 1;
  }
  unsigned short* regA = (unsigned short*)(w + OFF_RA);
  unsigned short* regB = (unsigned short*)(w + OFF_RA + (size_t)NT * PER_T_FULL);
  unsigned short* xbt  = regA;  // NT*N*128
  unsigned short* Q    = regA;  // NT*N*256 (xbt dead by then)
  unsigned short* P128 = regB;  // NT*N*128
  unsigned short* P2   = regB;  // NT*N*256 (P128 dead by then)

  hipMemsetAsync(d_ws, 0, ZERO_BYTES, stream);

  prep_kernel<<<1920, 256, 0, stream>>>(W1, W2, Wih, Whh, W1bT, W2bT, WihT, WhhT);

  dim3 te_grid(T_, ECH);
  histp<<<te_grid, 1024, 0, stream>>>(ei, ea, degp, cnt16);
  scanT<<<T_, 1024, 0, stream>>>(cnt16, degp, cp, dinv);
  pcount<<<te_grid, 256, 0, stream>>>(cnt16, pcnt);
  partS<<<1, 64, 0, stream>>>(pcnt, poff);
  partW<<<te_grid, 512, 0, stream>>>(ei, ea, dinv, poff, ebin);
  fillB2<<<dim3(T_, NB), 512, 0, stream>>>(ebin, cp);

  for (int t0 = 0; t0 < T_; t0 += NT) {
    const int nt = (T_ - t0) < NT ? (T_ - t0) : NT;
    castx_kernel<<<dim3(2500, nt), 256, 0, stream>>>(x, xbt, t0);
    agg128<<<nt * 5000, 256, 0, stream>>>(xbt, P128, (const uint2*)ebin, cp, dinv, t0, nt);
    gemm_bf16<FIN_, false><<<dim3(313, 2, nt), 256, 0, stream>>>(P128, W1bT, b1, Q, nullptr, t0);
    agg256<<<nt * 5000, 256, 0, stream>>>(Q, P2, (const uint2*)ebin, cp, dinv, t0, nt);
    gemm_bf16<H_, true><<<dim3(313, 2, nt), 256, 0, stream>>>(P2, W2bT, b2, nullptr, emb, t0);
  }
  gx_kernel<<<T_, 768, 0, stream>>>(emb, WihT, bih, GX);
  gru2_kernel<<<1, 768, 0, stream>>>(GX, WhhT, bhh, Wc, bc, out);
}

// Round 15
// 1004.658 us; speedup vs baseline: 1.2774x; 1.0683x over previous
//
#include <hip/hip_runtime.h>
#include <hip/hip_fp16.h>
#include <math.h>

#define T_ 12
#define N_ 20000
#define E_ 320000
#define FIN_ 128
#define H_ 256
#define G_ 256
#define C_ 10
#define ECH 8
#define EPC (E_ / ECH)   // 40000 edges per chunk
#define NB 20            // node buckets of 1024 (bucket = node >> 10)
#define BNODES 1024
#define CAPF 20480       // fillB2 LDS staging recs (mean 16384, +32 sigma)

typedef __attribute__((ext_vector_type(8))) short bf16x8;
typedef __attribute__((ext_vector_type(4))) float f32x4;

// ---------------- workspace layout (bytes) ----------------
static const size_t OFF_EMB   = 0;          // T*256 f32 (zeroed each launch)
static const size_t ZERO_BYTES= 12288;
static const size_t OFF_DINV  = 12288;      // T*N f32            -> 972288
static const size_t OFF_CP    = 972288;     // T*(N+1) i32 padded -> 1932544
static const size_t OFF_PCNT  = 1932544;    // T*ECH*NB u32       -> 1940224
static const size_t OFF_POFF  = 1940224;    // T*168 u32          -> 1948288
static const size_t OFF_W1BT  = 1948288;    // 256x128 bf16       -> 2013824
static const size_t OFF_W2BT  = 2013824;    // 256x256 bf16       -> 2144896
static const size_t OFF_WIHT  = 2144896;    // 256x768 f32        -> 2931328
static const size_t OFF_WHHT  = 2931328;    // 256x768 f32        -> 3717760
static const size_t OFF_GX    = 3717760;    // 12x768 f32         -> 3754624, pad
static const size_t OFF_EBIN  = 3754752;    // T*E uint2          -> 34474752
// DEGP (7.68MB) and CNT16 (3.84MB) alias inside EBIN: dead before partW writes
static const size_t OFF_DEGP  = 3754752;    // T*ECH*N f32  [dead after scanT]
static const size_t OFF_CNT16 = 11434752;   // T*ECH*N u16  [dead after scanT]
static const size_t OFF_RA    = 34474752;   // region A: NT*10.24MB (xbt then Q)
static const size_t PER_T_FULL= 10240000;   // N*256*2

__device__ __forceinline__ float bf2f(unsigned short u) {
  return __uint_as_float(((unsigned int)u) << 16);
}
__device__ __forceinline__ unsigned short f2bf(float f) {
  unsigned int u = __float_as_uint(f);
  unsigned int r = (u + 0x7FFFu + ((u >> 16) & 1u)) >> 16;  // RNE
  return (unsigned short)r;
}
__device__ __forceinline__ float bflo(unsigned int u) { return __uint_as_float(u << 16); }
__device__ __forceinline__ float bfhi(unsigned int u) { return __uint_as_float(u & 0xFFFF0000u); }
__device__ __forceinline__ unsigned int packbf(float lo, float hi) {
  return (unsigned int)f2bf(lo) | ((unsigned int)f2bf(hi) << 16);
}

// ---------------- partial histogram + fused bucket counts ----------------
__global__ __launch_bounds__(1024) void histp(const int* __restrict__ ei,
                                              const float* __restrict__ ea,
                                              float* __restrict__ degp,
                                              unsigned short* __restrict__ cnt16,
                                              unsigned int* __restrict__ pcnt) {
  __shared__ float degs[N_];            // 80 KB
  __shared__ unsigned int cntp[N_ / 2]; // 40 KB
  __shared__ unsigned int psum[NB];
  const int t = blockIdx.x, ech = blockIdx.y;
  const int tid = threadIdx.x;
  for (int i = tid; i < N_; i += 1024) degs[i] = 0.f;
  for (int i = tid; i < N_ / 2; i += 1024) cntp[i] = 0u;
  if (tid < NB) psum[tid] = 0u;
  __syncthreads();
  const int* col = ei + (size_t)t * 2 * E_ + E_ + ech * EPC;
  const float* wt = ea + (size_t)t * E_ + ech * EPC;
  for (int e = tid; e < EPC; e += 1024) {
    int c = col[e];
    atomicAdd(&degs[c], wt[e]);
    atomicAdd(&cntp[c >> 1], 1u << ((c & 1) * 16));
  }
  __syncthreads();
  float* dp = degp + ((size_t)t * ECH + ech) * N_;
  unsigned short* cp16 = cnt16 + ((size_t)t * ECH + ech) * N_;
  for (int i = tid; i < N_; i += 1024) {
    dp[i] = degs[i];
    cp16[i] = (unsigned short)((cntp[i >> 1] >> ((i & 1) * 16)) & 0xFFFFu);
  }
  // fused bucket counts: word i holds nodes 2i,2i+1 -> bucket i>>9 (1024-node buckets)
  for (int i = tid; i < N_ / 2; i += 1024) {
    unsigned int v = cntp[i];
    atomicAdd(&psum[i >> 9], (v & 0xFFFFu) + (v >> 16));
  }
  __syncthreads();
  if (tid < NB) pcnt[((size_t)t * ECH + ech) * NB + tid] = psum[tid];
}

// ---------------- sum partials, scan -> colptr, dinv ----------------
__global__ __launch_bounds__(1024) void scanT(const unsigned short* __restrict__ cnt16,
                                              const float* __restrict__ degp,
                                              int* __restrict__ colptr,
                                              float* __restrict__ dinv) {
  const int t = blockIdx.x;
  __shared__ int s[1024];
  const int tid = threadIdx.x;
  int base = 0;
  for (int c0 = 0; c0 < N_; c0 += 1024) {
    int n = c0 + tid;
    int tot = 0;
    float dg = 0.f;
    if (n < N_) {
#pragma unroll
      for (int ch = 0; ch < ECH; ++ch) {
        tot += cnt16[((size_t)t * ECH + ch) * N_ + n];
        dg += degp[((size_t)t * ECH + ch) * N_ + n];
      }
    }
    s[tid] = tot;
    __syncthreads();
    for (int off = 1; off < 1024; off <<= 1) {
      int add = (tid >= off) ? s[tid - off] : 0;
      __syncthreads();
      s[tid] += add;
      __syncthreads();
    }
    if (n < N_) {
      colptr[t * (N_ + 1) + n] = base + s[tid] - tot;
      dinv[t * N_ + n] = rsqrtf(dg + 1.0f);
    }
    base += s[1023];
    __syncthreads();
  }
  if (tid == 0) colptr[t * (N_ + 1) + N_] = base;
}

// ---------------- per-(bucket, chunk) stream offsets ----------------
__global__ void partS(const unsigned int* __restrict__ pcnt,
                      unsigned int* __restrict__ poff) {
  const int t = threadIdx.x;
  if (t >= T_) return;
  unsigned int run = 0;
  for (int b = 0; b < NB; ++b)
    for (int ech = 0; ech < ECH; ++ech) {
      poff[t * 168 + b * 8 + ech] = run;
      run += pcnt[((size_t)t * ECH + ech) * NB + b];
    }
  poff[t * 168 + 160] = run;
}

// ---------------- partition scatter: each edge touched once ----------------
__global__ __launch_bounds__(512) void partW(const int* __restrict__ ei,
                                             const float* __restrict__ ea,
                                             const float* __restrict__ dinv,
                                             const unsigned int* __restrict__ poff,
                                             uint2* __restrict__ ebin) {
  __shared__ unsigned int cursor[NB];
  const int t = blockIdx.x, ech = blockIdx.y;
  const int tid = threadIdx.x;
  if (tid < NB) cursor[tid] = poff[t * 168 + tid * 8 + ech];
  __syncthreads();
  const int eoff = ech * EPC;
  const int* rowp = ei + (size_t)t * 2 * E_ + eoff;
  const int* colp = rowp + E_;
  const float* wt = ea + (size_t)t * E_ + eoff;
  const float* dv = dinv + (size_t)t * N_;
  uint2* eb = ebin + (size_t)t * E_;
  for (int e = tid; e < EPC; e += 512) {
    int c = colp[e], r = rowp[e];
    float nm = dv[r] * wt[e] * dv[c];
    unsigned int pos = atomicAdd(&cursor[c >> 10], 1u);
    uint2 rec;
    rec.x = (unsigned int)(c & 1023) | ((unsigned int)r << 16);
    rec.y = (unsigned int)__half_as_ushort(__float2half(nm));
    eb[pos] = rec;
  }
}

// ---------------- CSR fill IN-PLACE: bucket-local LDS scatter; expand to {row, nm f32} ----------------
__global__ __launch_bounds__(512) void fillB2(uint2* __restrict__ ebin,
                                              const int* __restrict__ colptr) {
  __shared__ unsigned int data[CAPF];   // 80 KB packed (row u16 | nm f16)
  __shared__ unsigned int offp[BNODES]; // 4 KB
  const int t = blockIdx.x, b = blockIdx.y;
  const int tid = threadIdx.x;
  const int nlo = b << 10;
  const int nnodes = (N_ - nlo < BNODES) ? (N_ - nlo) : BNODES;
  const int* cp = colptr + t * (N_ + 1);
  const int base = cp[nlo];
  const int bsize = cp[nlo + nnodes] - base;
  for (int i = tid; i < nnodes; i += 512) offp[i] = (unsigned int)(cp[nlo + i] - base);
  __syncthreads();
  uint2* eb = ebin + (size_t)t * E_ + base;
  for (int i = tid; i < bsize; i += 512) {
    uint2 rec = eb[i];
    unsigned int cl = rec.x & 0xFFFFu;
    unsigned int rec4 = (rec.x >> 16) | (rec.y << 16);  // row | f16nm<<16
    unsigned int pos = atomicAdd(&offp[cl], 1u);
    if (pos < CAPF) data[pos] = rec4;  // CAPF = +32 sigma: overflow unreachable
  }
  __syncthreads();  // all reads of eb complete before in-place writes
  const int lim = bsize < CAPF ? bsize : CAPF;
  for (int i = tid; i < lim; i += 512) {
    unsigned int rec4 = data[i];
    uint2 o;
    o.x = rec4 & 0xFFFFu;  // row
    o.y = __float_as_uint(__half2float(__ushort_as_half((unsigned short)(rec4 >> 16))));
    eb[i] = o;
  }
}

// ---------------- weight prep ----------------
__global__ __launch_bounds__(256) void prep_kernel(const float* __restrict__ W1,
                                                   const float* __restrict__ W2,
                                                   const float* __restrict__ Wih,
                                                   const float* __restrict__ Whh,
                                                   unsigned short* __restrict__ W1bT,
                                                   unsigned short* __restrict__ W2bT,
                                                   float* __restrict__ WihT,
                                                   float* __restrict__ WhhT) {
  int idx = blockIdx.x * 256 + threadIdx.x;
  if (idx < 32768) {
    int n = idx >> 7, k = idx & 127;
    W1bT[idx] = f2bf(W1[k * 256 + n]);
  } else if (idx < 98304) {
    int j = idx - 32768;
    int n = j >> 8, k = j & 255;
    W2bT[j] = f2bf(W2[k * 256 + n]);
  } else if (idx < 294912) {
    int j = idx - 98304;
    int k = j / 768, c = j - k * 768;
    WihT[j] = Wih[c * 256 + k];
  } else if (idx < 491520) {
    int j = idx - 294912;
    int k = j / 768, c = j - k * 768;
    WhhT[j] = Whh[c * 256 + k];
  }
}

// ---------------- cast x_t fp32 -> bf16 (y = local t) ----------------
__global__ __launch_bounds__(256) void castx_kernel(const float* __restrict__ x,
                                                    unsigned short* __restrict__ xb,
                                                    int t_base) {
  const int tl = blockIdx.y;
  const int t = t_base + tl;
  const size_t q = (size_t)blockIdx.x * 256 + threadIdx.x;
  float4 v = ((const float4*)x)[(size_t)t * (N_ * FIN_ / 4) + q];
  ushort4 o;
  o.x = f2bf(v.x); o.y = f2bf(v.y); o.z = f2bf(v.z); o.w = f2bf(v.w);
  ((ushort4*)xb)[(size_t)tl * (N_ * FIN_ / 4) + q] = o;
}

// ---------------- full-sector gathers, depth-2 software pipeline ----------------
__device__ __forceinline__ void agg_decode(int nt, int t_base, int& t, int& tl, int& node) {
  int bid = blockIdx.x;
  int L = bid;
  if (nt > 1) {
    int chunk = (int)(gridDim.x >> 3);
    L = (bid & 7) * chunk + (bid >> 3);
  }
  tl = L / 5000;
  node = (L - tl * 5000) * 4 + ((int)threadIdx.x >> 6);
  t = t_base + nt > 1 ? t_base + tl : t_base + tl;  // (kept simple)
  t = t_base + tl;
}

// 128-ch: quarter-wave (16 lanes x 16B) per edge, stride 4; recs prefetched 2 iters ahead
__global__ __launch_bounds__(256) void agg128(const unsigned short* __restrict__ h,
                                              unsigned short* __restrict__ o,
                                              const uint2* __restrict__ erec2,
                                              const int* __restrict__ colptr,
                                              const float* __restrict__ dinv,
                                              int t_base, int nt) {
  int t, tl, node;
  agg_decode(nt, t_base, t, tl, node);
  const int q = ((int)threadIdx.x >> 4) & 3;
  const int l16 = threadIdx.x & 15;
  const int me = threadIdx.x & 63;
  const uint2* ert = erec2 + (size_t)t * E_;
  const int* cp = colptr + t * (N_ + 1);
  const unsigned short* ht = h + (size_t)tl * N_ * 128;
  float a0 = 0.f, a1 = 0.f, a2 = 0.f, a3 = 0.f, a4 = 0.f, a5 = 0.f, a6 = 0.f, a7 = 0.f;
  const int s0 = cp[node], s1 = cp[node + 1];
  const uint2 SAFE = {(unsigned int)node, 0u};
  {
    int i = s0 + q;
    uint2 r0 = (i < s1) ? ert[i] : SAFE;
    uint2 r1 = (i + 4 < s1) ? ert[i + 4] : SAFE;
    uint4 u0 = *(const uint4*)&ht[(size_t)r0.x * 128 + l16 * 8];
    for (int k = i; k < s1; k += 4) {
      uint2 r2 = (k + 8 < s1) ? ert[k + 8] : SAFE;
      uint4 u1 = *(const uint4*)&ht[(size_t)r1.x * 128 + l16 * 8];
      const float nm = __uint_as_float(r0.y);
      a0 = fmaf(nm, bflo(u0.x), a0); a1 = fmaf(nm, bfhi(u0.x), a1);
      a2 = fmaf(nm, bflo(u0.y), a2); a3 = fmaf(nm, bfhi(u0.y), a3);
      a4 = fmaf(nm, bflo(u0.z), a4); a5 = fmaf(nm, bfhi(u0.z), a5);
      a6 = fmaf(nm, bflo(u0.w), a6); a7 = fmaf(nm, bfhi(u0.w), a7);
      r0 = r1; r1 = r2; u0 = u1;
    }
  }
  if (q == 0) {
    const float di = dinv[(size_t)t * N_ + node];
    const float sw = di * di;
    uint4 us = *(const uint4*)&ht[(size_t)node * 128 + l16 * 8];
    a0 = fmaf(sw, bflo(us.x), a0); a1 = fmaf(sw, bfhi(us.x), a1);
    a2 = fmaf(sw, bflo(us.y), a2); a3 = fmaf(sw, bfhi(us.y), a3);
    a4 = fmaf(sw, bflo(us.z), a4); a5 = fmaf(sw, bfhi(us.z), a5);
    a6 = fmaf(sw, bflo(us.w), a6); a7 = fmaf(sw, bfhi(us.w), a7);
  }
  a0 += __shfl(a0, me | 16, 64); a1 += __shfl(a1, me | 16, 64);
  a2 += __shfl(a2, me | 16, 64); a3 += __shfl(a3, me | 16, 64);
  a4 += __shfl(a4, me | 16, 64); a5 += __shfl(a5, me | 16, 64);
  a6 += __shfl(a6, me | 16, 64); a7 += __shfl(a7, me | 16, 64);
  a0 += __shfl(a0, me | 32, 64); a1 += __shfl(a1, me | 32, 64);
  a2 += __shfl(a2, me | 32, 64); a3 += __shfl(a3, me | 32, 64);
  a4 += __shfl(a4, me | 32, 64); a5 += __shfl(a5, me | 32, 64);
  a6 += __shfl(a6, me | 32, 64); a7 += __shfl(a7, me | 32, 64);
  if (q == 0 && (me >> 4) == 0) {
    uint4 ov;
    ov.x = packbf(a0, a1); ov.y = packbf(a2, a3);
    ov.z = packbf(a4, a5); ov.w = packbf(a6, a7);
    *(uint4*)&o[((size_t)tl * N_ + node) * 128 + l16 * 8] = ov;
  }
}

// 256-ch: half-wave (32 lanes x 16B) per edge, stride 2; depth-2 pipeline
__global__ __launch_bounds__(256) void agg256(const unsigned short* __restrict__ h,
                                              unsigned short* __restrict__ o,
                                              const uint2* __restrict__ erec2,
                                              const int* __restrict__ colptr,
                                              const float* __restrict__ dinv,
                                              int t_base, int nt) {
  int t, tl, node;
  agg_decode(nt, t_base, t, tl, node);
  const int hh = ((int)threadIdx.x >> 5) & 1;
  const int l32 = threadIdx.x & 31;
  const int me = threadIdx.x & 63;
  const uint2* ert = erec2 + (size_t)t * E_;
  const int* cp = colptr + t * (N_ + 1);
  const unsigned short* ht = h + (size_t)tl * N_ * 256;
  float a0 = 0.f, a1 = 0.f, a2 = 0.f, a3 = 0.f, a4 = 0.f, a5 = 0.f, a6 = 0.f, a7 = 0.f;
  const int s0 = cp[node], s1 = cp[node + 1];
  const uint2 SAFE = {(unsigned int)node, 0u};
  {
    int i = s0 + hh;
    uint2 r0 = (i < s1) ? ert[i] : SAFE;
    uint2 r1 = (i + 2 < s1) ? ert[i + 2] : SAFE;
    uint4 u0 = *(const uint4*)&ht[(size_t)r0.x * 256 + l32 * 8];
    for (int k = i; k < s1; k += 2) {
      uint2 r2 = (k + 4 < s1) ? ert[k + 4] : SAFE;
      uint4 u1 = *(const uint4*)&ht[(size_t)r1.x * 256 + l32 * 8];
      const float nm = __uint_as_float(r0.y);
      a0 = fmaf(nm, bflo(u0.x), a0); a1 = fmaf(nm, bfhi(u0.x), a1);
      a2 = fmaf(nm, bflo(u0.y), a2); a3 = fmaf(nm, bfhi(u0.y), a3);
      a4 = fmaf(nm, bflo(u0.z), a4); a5 = fmaf(nm, bfhi(u0.z), a5);
      a6 = fmaf(nm, bflo(u0.w), a6); a7 = fmaf(nm, bfhi(u0.w), a7);
      r0 = r1; r1 = r2; u0 = u1;
    }
  }
  if (hh == 0) {
    const float di = dinv[(size_t)t * N_ + node];
    const float sw = di * di;
    uint4 us = *(const uint4*)&ht[(size_t)node * 256 + l32 * 8];
    a0 = fmaf(sw, bflo(us.x), a0); a1 = fmaf(sw, bfhi(us.x), a1);
    a2 = fmaf(sw, bflo(us.y), a2); a3 = fmaf(sw, bfhi(us.y), a3);
    a4 = fmaf(sw, bflo(us.z), a4); a5 = fmaf(sw, bfhi(us.z), a5);
    a6 = fmaf(sw, bflo(us.w), a6); a7 = fmaf(sw, bfhi(us.w), a7);
  }
  a0 += __shfl(a0, me | 32, 64); a1 += __shfl(a1, me | 32, 64);
  a2 += __shfl(a2, me | 32, 64); a3 += __shfl(a3, me | 32, 64);
  a4 += __shfl(a4, me | 32, 64); a5 += __shfl(a5, me | 32, 64);
  a6 += __shfl(a6, me | 32, 64); a7 += __shfl(a7, me | 32, 64);
  if (hh == 0) {
    uint4 ov;
    ov.x = packbf(a0, a1); ov.y = packbf(a2, a3);
    ov.z = packbf(a4, a5); ov.w = packbf(a6, a7);
    *(uint4*)&o[((size_t)tl * N_ + node) * 256 + l32 * 8] = ov;
  }
}

// ---------------- bf16 MFMA GEMM (z = local t); MEAN fuses column-mean ----------------
template <int K, bool MEAN>
__global__ __launch_bounds__(256) void gemm_bf16(const unsigned short* __restrict__ A,
                                                 const unsigned short* __restrict__ BT,
                                                 const float* __restrict__ bias,
                                                 unsigned short* __restrict__ C,
                                                 float* __restrict__ embp,
                                                 int t_base) {
  constexpr int LD = K + 8;
  __shared__ unsigned short As[64 * LD];
  __shared__ float cs[128];
  const int tid = threadIdx.x;
  const int tl = blockIdx.z;
  const int bm = blockIdx.x * 64;
  const int bn = blockIdx.y * 128;
  const unsigned short* At = A + (size_t)tl * N_ * K;
  if (MEAN && tid < 128) cs[tid] = 0.f;
  {
    constexpr int CPR = K / 8;
    constexpr int CH = 64 * CPR / 256;
#pragma unroll
    for (int i = 0; i < CH; ++i) {
      int chunk = tid + i * 256;
      int r = chunk / CPR;
      int ck = (chunk - r * CPR) * 8;
      int row = bm + r;
      if (row >= N_) row = N_ - 1;
      *(bf16x8*)&As[r * LD + ck] = *(const bf16x8*)&At[(size_t)row * K + ck];
    }
  }
  __syncthreads();
  const int w = tid >> 6, l = tid & 63;
  const int l16 = l & 15, lk = l >> 4;
  const int rbase = (w >> 1) * 32;
  const int colbase = bn + (w & 1) * 64;
  f32x4 acc[2][4] = {};
  for (int ks = 0; ks < K; ks += 32) {
    bf16x8 a[2], b[4];
#pragma unroll
    for (int m = 0; m < 2; ++m)
      a[m] = *(const bf16x8*)&As[(rbase + m * 16 + l16) * LD + ks + lk * 8];
#pragma unroll
    for (int n = 0; n < 4; ++n)
      b[n] = *(const bf16x8*)&BT[(size_t)(colbase + n * 16 + l16) * K + ks + lk * 8];
#pragma unroll
    for (int m = 0; m < 2; ++m)
#pragma unroll
      for (int n = 0; n < 4; ++n)
        acc[m][n] = __builtin_amdgcn_mfma_f32_16x16x32_bf16(a[m], b[n], acc[m][n], 0, 0, 0);
  }
#pragma unroll
  for (int n = 0; n < 4; ++n) {
    int col = colbase + n * 16 + l16;
    float bv = bias[col];
    float psum = 0.f;
#pragma unroll
    for (int m = 0; m < 2; ++m) {
      int row0 = bm + rbase + m * 16 + lk * 4;
#pragma unroll
      for (int r = 0; r < 4; ++r) {
        int row = row0 + r;
        if (row < N_) {
          float v = fmaxf(acc[m][n][r] + bv, 0.f);
          if (MEAN) psum += v;
          else C[((size_t)tl * N_ + row) * 256 + col] = f2bf(v);
        }
      }
    }
    if (MEAN) atomicAdd(&cs[col - bn], psum);
  }
  if (MEAN) {
    __syncthreads();
    if (tid < 128)
      atomicAdd(&embp[(t_base + tl) * 256 + bn + tid], cs[tid] * (1.0f / N_));
  }
}

// ---------------- GX[t] = Wih @ emb_t + bih ----------------
__global__ __launch_bounds__(768) void gx_kernel(const float* __restrict__ emb,
                                                 const float* __restrict__ WihT,
                                                 const float* __restrict__ bih,
                                                 float* __restrict__ GX) {
  const int t = blockIdx.x;
  const int tid = threadIdx.x;
  __shared__ float se[256];
  if (tid < 256) se[tid] = emb[t * 256 + tid];
  __syncthreads();
  float p0 = 0.f, p1 = 0.f, p2 = 0.f, p3 = 0.f;
#pragma unroll 8
  for (int k = 0; k < 256; k += 4) {
    p0 = fmaf(WihT[(size_t)(k + 0) * 768 + tid], se[k + 0], p0);
    p1 = fmaf(WihT[(size_t)(k + 1) * 768 + tid], se[k + 1], p1);
    p2 = fmaf(WihT[(size_t)(k + 2) * 768 + tid], se[k + 2], p2);
    p3 = fmaf(WihT[(size_t)(k + 3) * 768 + tid], se[k + 3], p3);
  }
  GX[t * 768 + tid] = (p0 + p1) + (p2 + p3) + bih[tid];
}

// ---------------- sequential GRU + final linear ----------------
__global__ __launch_bounds__(768) void gru2_kernel(const float* __restrict__ GX,
                                                   const float* __restrict__ WhhT,
                                                   const float* __restrict__ bhh,
                                                   const float* __restrict__ Wc,
                                                   const float* __restrict__ bc,
                                                   float* __restrict__ out) {
  __shared__ float sh[256];
  __shared__ float sgh[768];
  const int tid = threadIdx.x;
  if (tid < 256) sh[tid] = 0.f;
  __syncthreads();
  for (int t = 0; t < T_; ++t) {
    float p0 = 0.f, p1 = 0.f, p2 = 0.f, p3 = 0.f;
#pragma unroll 8
    for (int k = 0; k < 256; k += 4) {
      p0 = fmaf(WhhT[(size_t)(k + 0) * 768 + tid], sh[k + 0], p0);
      p1 = fmaf(WhhT[(size_t)(k + 1) * 768 + tid], sh[k + 1], p1);
      p2 = fmaf(WhhT[(size_t)(k + 2) * 768 + tid], sh[k + 2], p2);
      p3 = fmaf(WhhT[(size_t)(k + 3) * 768 + tid], sh[k + 3], p3);
    }
    sgh[tid] = (p0 + p1) + (p2 + p3) + bhh[tid];
    __syncthreads();
    if (tid < 256) {
      const float* gx = &GX[t * 768];
      float r = 1.f / (1.f + __expf(-(gx[tid] + sgh[tid])));
      float z = 1.f / (1.f + __expf(-(gx[256 + tid] + sgh[256 + tid])));
      float n = tanhf(gx[512 + tid] + r * sgh[512 + tid]);
      sh[tid] = (1.f - z) * n + z * sh[tid];
    }
    __syncthreads();
  }
  const int wv = tid >> 6, lane = tid & 63;
  if (wv < C_) {
    float p = 0.f;
#pragma unroll
    for (int i = 0; i < 4; ++i) {
      int j = lane + 64 * i;
      p += sh[j] * Wc[(size_t)j * C_ + wv];
    }
    for (int off = 32; off > 0; off >>= 1) p += __shfl_down(p, off);
    if (lane == 0) out[wv] = p + bc[wv];
  }
}

extern "C" void kernel_launch(void* const* d_in, const int* in_sizes, int n_in,
                              void* d_out, int out_size, void* d_ws, size_t ws_size,
                              hipStream_t stream) {
  const float* x   = (const float*)d_in[0];
  const int*   ei  = (const int*)d_in[1];
  const float* ea  = (const float*)d_in[2];
  const float* W1  = (const float*)d_in[3];
  const float* b1  = (const float*)d_in[4];
  const float* W2  = (const float*)d_in[5];
  const float* b2  = (const float*)d_in[6];
  const float* Wih = (const float*)d_in[7];
  const float* Whh = (const float*)d_in[8];
  const float* bih = (const float*)d_in[9];
  const float* bhh = (const float*)d_in[10];
  const float* Wc  = (const float*)d_in[11];
  const float* bc  = (const float*)d_in[12];
  float* out = (float*)d_out;

  char* w = (char*)d_ws;
  float* emb   = (float*)(w + OFF_EMB);
  float* dinv  = (float*)(w + OFF_DINV);
  int*   cp    = (int*)(w + OFF_CP);
  unsigned int* pcnt = (unsigned int*)(w + OFF_PCNT);
  unsigned int* poff = (unsigned int*)(w + OFF_POFF);
  unsigned short* W1bT = (unsigned short*)(w + OFF_W1BT);
  unsigned short* W2bT = (unsigned short*)(w + OFF_W2BT);
  float* WihT  = (float*)(w + OFF_WIHT);
  float* WhhT  = (float*)(w + OFF_WHHT);
  float* GX    = (float*)(w + OFF_GX);
  float* degp  = (float*)(w + OFF_DEGP);
  unsigned short* cnt16 = (unsigned short*)(w + OFF_CNT16);
  uint2* ebin  = (uint2*)(w + OFF_EBIN);

  // adaptive group size
  int NT = 1;
  if (ws_size > OFF_RA + 2 * PER_T_FULL) {
    size_t avail = ws_size - OFF_RA;
    size_t nt = avail / (2 * PER_T_FULL);
    NT = (int)(nt < 12 ? nt : 12);
    if (NT < 1) NT = 1;
  }
  unsigned short* regA = (unsigned short*)(w + OFF_RA);
  unsigned short* regB = (unsigned short*)(w + OFF_RA + (size_t)NT * PER_T_FULL);
  unsigned short* xbt  = regA;  // NT*N*128
  unsigned short* Q    = regA;  // NT*N*256 (xbt dead by then)
  unsigned short* P128 = regB;  // NT*N*128
  unsigned short* P2   = regB;  // NT*N*256 (P128 dead by then)

  hipMemsetAsync(d_ws, 0, ZERO_BYTES, stream);

  prep_kernel<<<1920, 256, 0, stream>>>(W1, W2, Wih, Whh, W1bT, W2bT, WihT, WhhT);

  dim3 te_grid(T_, ECH);
  histp<<<te_grid, 1024, 0, stream>>>(ei, ea, degp, cnt16, pcnt);
  scanT<<<T_, 1024, 0, stream>>>(cnt16, degp, cp, dinv);
  partS<<<1, 64, 0, stream>>>(pcnt, poff);
  partW<<<te_grid, 512, 0, stream>>>(ei, ea, dinv, poff, ebin);
  fillB2<<<dim3(T_, NB), 512, 0, stream>>>(ebin, cp);

  for (int t0 = 0; t0 < T_; t0 += NT) {
    const int nt = (T_ - t0) < NT ? (T_ - t0) : NT;
    castx_kernel<<<dim3(2500, nt), 256, 0, stream>>>(x, xbt, t0);
    agg128<<<nt * 5000, 256, 0, stream>>>(xbt, P128, (const uint2*)ebin, cp, dinv, t0, nt);
    gemm_bf16<FIN_, false><<<dim3(313, 2, nt), 256, 0, stream>>>(P128, W1bT, b1, Q, nullptr, t0);
    agg256<<<nt * 5000, 256, 0, stream>>>(Q, P2, (const uint2*)ebin, cp, dinv, t0, nt);
    gemm_bf16<H_, true><<<dim3(313, 2, nt), 256, 0, stream>>>(P2, W2bT, b2, nullptr, emb, t0);
  }
  gx_kernel<<<T_, 768, 0, stream>>>(emb, WihT, bih, GX);
  gru2_kernel<<<1, 768, 0, stream>>>(GX, WhhT, bhh, Wc, bc, out);
}